// Round 17
// baseline (197.237 us; speedup 1.0000x reference)
//
#include <hip/hip_runtime.h>
#include <hip/hip_bf16.h>

#define NB  4
#define NH  8
#define NC  16
#define ND  64
#define NN  16384
#define NG  32
#define NG3 32768
#define NKV 152
#define KEPS 1e-5f
#define TN  256   // points per k_front4 block

typedef __attribute__((ext_vector_type(8))) short bf16x8;
typedef __attribute__((ext_vector_type(4))) float f32x4;

__device__ __forceinline__ unsigned pack_bf2(float lo, float hi) {
    __hip_bfloat16 a = __float2bfloat16(lo);
    __hip_bfloat16 b = __float2bfloat16(hi);
    return (unsigned)(*(unsigned short*)&a) | ((unsigned)(*(unsigned short*)&b) << 16);
}
__device__ __forceinline__ float bf_lo(unsigned u) { return __uint_as_float(u << 16); }
__device__ __forceinline__ float bf_hi(unsigned u) { return __uint_as_float(u & 0xffff0000u); }

// ---------------------------------------------------------------------------
// Kernel 0: fast zero of hist (4 MB).
// ---------------------------------------------------------------------------
__global__ __launch_bounds__(256)
void k_zero(uint4* __restrict__ p)
{
    p[(long)blockIdx.x * 256 + threadIdx.x] = make_uint4(0, 0, 0, 0);
}

// ---------------------------------------------------------------------------
// Kernel 1: front — 4 head-group blocks per point-tile.
// ---------------------------------------------------------------------------
__global__ __launch_bounds__(256)
void k_front4(const float* __restrict__ x,      // [B,D,N]
              const float* __restrict__ orig,   // [B,3,N]
              const float* __restrict__ wkv,    // [152,64]
              const float* __restrict__ kg, const float* __restrict__ kb,
              const float* __restrict__ km, const float* __restrict__ kvv,
              const float* __restrict__ vg, const float* __restrict__ vb,
              const float* __restrict__ vm, const float* __restrict__ vv,
              const float* __restrict__ Wt,     // [8,3,3]
              const float* __restrict__ bt,     // [8,3]
              unsigned short* __restrict__ valb, // [B,H,N,C] bf16
              float4* __restrict__ pre,         // [B,H,N]
              int* __restrict__ hist)           // [B*H*32768]
{
    __shared__ unsigned short xb[TN * 72];      // bf16 x tile [n][d], pitch 72
    __shared__ float wk[6 * ND];                // this group's key rows
    __shared__ float ksc[6], ksh[6], vsc[32], vsh[32], wts[18], bts[6];
    const int tid = threadIdx.x;
    const int hg   = blockIdx.x & 3;            // head group: heads hg*2, hg*2+1
    const int tile = (blockIdx.x >> 2) & 63;
    const int b    = blockIdx.x >> 8;
    const int n0 = tile * TN;
    const int n  = n0 + tid;

    for (int i = tid; i < 6 * ND; i += 256) wk[i] = wkv[hg * 384 + i];
    if (tid < 6) {
        int ch = hg * 6 + tid;
        float s = rsqrtf(kvv[ch] + KEPS) * kg[ch];
        ksc[tid] = s;
        ksh[tid] = kb[ch] - km[ch] * s;
    }
    if (tid < 32) {
        int ch = hg * 32 + tid;
        float s = rsqrtf(vv[ch] + KEPS) * vg[ch];
        vsc[tid] = s;
        vsh[tid] = vb[ch] - vm[ch] * s;
    }
    if (tid < 18) wts[tid] = Wt[hg * 18 + tid];
    if (tid < 6)  bts[tid] = bt[hg * 6 + tid];

    float xr[ND];
    #pragma unroll
    for (int d = 0; d < ND; ++d)
        xr[d] = x[((long)b * ND + d) * NN + n];
    #pragma unroll
    for (int j = 0; j < 8; ++j) {
        uint4 q;
        q.x = pack_bf2(xr[8*j+0], xr[8*j+1]);
        q.y = pack_bf2(xr[8*j+2], xr[8*j+3]);
        q.z = pack_bf2(xr[8*j+4], xr[8*j+5]);
        q.w = pack_bf2(xr[8*j+6], xr[8*j+7]);
        *(uint4*)(xb + tid * 72 + j * 8) = q;
    }
    __syncthreads();

    // keys: this group's 6 rows
    float ko[6];
    #pragma unroll 1
    for (int o = 0; o < 6; o += 3) {
        float s0 = 0.f, s1 = 0.f, s2 = 0.f;
        #pragma unroll
        for (int dq = 0; dq < 16; ++dq) {
            const float4 w0 = *(const float4*)&wk[(o + 0) * ND + dq * 4];
            const float4 w1 = *(const float4*)&wk[(o + 1) * ND + dq * 4];
            const float4 w2 = *(const float4*)&wk[(o + 2) * ND + dq * 4];
            float a0 = xr[4*dq], a1 = xr[4*dq+1], a2 = xr[4*dq+2], a3 = xr[4*dq+3];
            s0 = fmaf(w0.x, a0, fmaf(w0.y, a1, fmaf(w0.z, a2, fmaf(w0.w, a3, s0))));
            s1 = fmaf(w1.x, a0, fmaf(w1.y, a1, fmaf(w1.z, a2, fmaf(w1.w, a3, s1))));
            s2 = fmaf(w2.x, a0, fmaf(w2.y, a1, fmaf(w2.z, a2, fmaf(w2.w, a3, s2))));
        }
        ko[o + 0] = fmaf(s0, ksc[o + 0], ksh[o + 0]);
        ko[o + 1] = fmaf(s1, ksc[o + 1], ksh[o + 1]);
        ko[o + 2] = fmaf(s2, ksc[o + 2], ksh[o + 2]);
    }

    // values via MFMA: wave wv -> head hg*2+(wv&1), nb range (wv>>1)*8..+8
    {
        const int lane = tid & 63;
        const int wv = tid >> 6;
        const int l15 = lane & 15, l4 = lane >> 4;
        const int hl = wv & 1;
        const int h = hg * 2 + hl;
        const int ocg = h * 16 + l15;
        const int nbr = (wv >> 1) * 8;
        const float bsc = vsc[hl * 16 + l15];
        const float bsh = vsh[hl * 16 + l15];

        bf16x8 bfr[2];
        #pragma unroll
        for (int ks = 0; ks < 2; ++ks) {
            const float* wp = wkv + (24 + ocg) * ND + ks * 32 + l4 * 8;
            float4 a = *(const float4*)wp;
            float4 c = *(const float4*)(wp + 4);
            uint4 q;
            q.x = pack_bf2(a.x, a.y); q.y = pack_bf2(a.z, a.w);
            q.z = pack_bf2(c.x, c.y); q.w = pack_bf2(c.z, c.w);
            bfr[ks] = *(bf16x8*)&q;
        }

        #pragma unroll 1
        for (int nbi = 0; nbi < 8; ++nbi) {
            int nb = nbr + nbi;
            bf16x8 a0 = *(const bf16x8*)(xb + (nb * 16 + l15) * 72 + l4 * 8);
            bf16x8 a1 = *(const bf16x8*)(xb + (nb * 16 + l15) * 72 + 32 + l4 * 8);
            f32x4 acc = (f32x4){0.f, 0.f, 0.f, 0.f};
            acc = __builtin_amdgcn_mfma_f32_16x16x32_bf16(a0, bfr[0], acc, 0, 0, 0);
            acc = __builtin_amdgcn_mfma_f32_16x16x32_bf16(a1, bfr[1], acc, 0, 0, 0);
            unsigned short* vp = valb + (((long)(b * NH + h) * NN + n0 + nb * 16 + l4 * 4) * NC) + l15;
            #pragma unroll
            for (int r = 0; r < 4; ++r) {
                __hip_bfloat16 hb = __float2bfloat16(fmaf(acc[r], bsc, bsh));
                vp[r * NC] = *(unsigned short*)&hb;
            }
        }
    }

    // lattice coords for this group's 2 heads
    const float o0 = orig[((long)b * 3 + 0) * NN + n];
    const float o1 = orig[((long)b * 3 + 1) * NN + n];
    const float o2 = orig[((long)b * 3 + 2) * NN + n];

    #pragma unroll 1
    for (int lh = 0; lh < 2; ++lh) {
        float p0 = o0 + ko[lh * 3 + 0];
        float p1 = o1 + ko[lh * 3 + 1];
        float p2 = o2 + ko[lh * 3 + 2];
        float t0 = fmaf(wts[lh * 9 + 0], p0, fmaf(wts[lh * 9 + 1], p1, fmaf(wts[lh * 9 + 2], p2, bts[lh * 3 + 0])));
        float t1 = fmaf(wts[lh * 9 + 3], p0, fmaf(wts[lh * 9 + 4], p1, fmaf(wts[lh * 9 + 5], p2, bts[lh * 3 + 1])));
        float t2 = fmaf(wts[lh * 9 + 6], p0, fmaf(wts[lh * 9 + 7], p1, fmaf(wts[lh * 9 + 8], p2, bts[lh * 3 + 2])));
        float l0 = tanhf(t0), l1 = tanhf(t1), l2 = tanhf(t2);
        float pos0 = (l0 + 1.f) * 15.5f;
        float pos1 = (l1 + 1.f) * 15.5f;
        float pos2 = (l2 + 1.f) * 15.5f;
        float b0 = fminf(fmaxf(floorf(pos0), 0.f), 30.f);
        float b1 = fminf(fmaxf(floorf(pos1), 0.f), 30.f);
        float b2 = fminf(fmaxf(floorf(pos2), 0.f), 30.f);
        int ix = (int)b0, iy = (int)b1, iz = (int)b2;
        float fx = pos0 - b0, fy = pos1 - b1, fz = pos2 - b2;
        int ibase = (ix * NG + iy) * NG + iz;
        float4 pr;
        pr.x = __int_as_float(ibase);
        pr.y = fx; pr.z = fy; pr.w = fz;
        int bh = b * NH + hg * 2 + lh;
        pre[(long)bh * NN + n] = pr;
        atomicAdd(&hist[bh * NG3 + ibase], 1);
    }
}

// ---------------------------------------------------------------------------
// Kernel 1b: per-bh exclusive prefix scan over 32768 cell counts.
// ---------------------------------------------------------------------------
__global__ __launch_bounds__(1024)
void k_scan_cells(const int* __restrict__ hist, int* __restrict__ offs,
                  int* __restrict__ offs_live)
{
    __shared__ int tsum[1024];
    const int bh = blockIdx.x, tid = threadIdx.x;
    const int* hb = hist + (long)bh * NG3;

    int s = 0;
    #pragma unroll 4
    for (int j = 0; j < 32; ++j) s += hb[tid * 32 + j];
    tsum[tid] = s;
    __syncthreads();
    for (int d = 1; d < 1024; d <<= 1) {
        int t = (tid >= d) ? tsum[tid - d] : 0;
        __syncthreads();
        tsum[tid] += t;
        __syncthreads();
    }
    int run = bh * NN + tsum[tid] - s;
    int* ob = offs + (long)bh * NG3;
    int* lb = offs_live + (long)bh * NG3;
    #pragma unroll 4
    for (int j = 0; j < 32; ++j) {
        int c = tid * 32 + j;
        ob[c] = run;
        lb[c] = run;
        run += hb[c];
    }
}

// ---------------------------------------------------------------------------
// Kernel 1c: scatter records into cell order. Record = 3 x uint4 = 48 B.
// XCD-grouped bh mapping (4-bh working set per XCD).
// ---------------------------------------------------------------------------
__global__ __launch_bounds__(256)
void k_scatter2(const float4* __restrict__ pre, const unsigned short* __restrict__ valb,
                int* __restrict__ offs_live, uint4* __restrict__ rec)
{
    const int bh   = 8 * ((blockIdx.x >> 3) & 3) + (blockIdx.x & 7);
    const int tile = blockIdx.x >> 5;
    long t = (long)bh * NN + tile * 256 + threadIdx.x;
    float4 r = pre[t];
    int ibase = __float_as_int(r.x);
    int slot = atomicAdd(&offs_live[(long)bh * NG3 + ibase], 1);
    const uint4* vp = (const uint4*)(valb + t * NC);
    uint4 v0 = vp[0], v1 = vp[1];
    uint4* out = rec + (long)slot * 3;
    out[0] = make_uint4(__float_as_uint(r.y), __float_as_uint(r.z), __float_as_uint(r.w), 0u);
    out[1] = v0;
    out[2] = v1;
}

// ---------------------------------------------------------------------------
// Kernel 2: splat7 — block owns TWO output x-planes {2kp, 2kp+1}; stages
// record planes {2kp-1, 2kp, 2kp+1} ONCE each (middle plane feeds both
// accumulators in one walk). 25% fewer record reads + barriers vs splat6.
// Atomic-free, BF16 out.
// ---------------------------------------------------------------------------
__global__ __launch_bounds__(1024)
void k_splat7(const uint4* __restrict__ rec, const int* __restrict__ hist,
              const int* __restrict__ offs, unsigned short* __restrict__ gridb)
{
    __shared__ uint4 sr[1024 * 3];   // 48 KB chunk
    const int tid = threadIdx.x;
    const int bh = blockIdx.x & 31;
    const int kp = blockIdx.x >> 5;          // owns planes 2kp, 2kp+1
    const int y = tid >> 5, z = tid & 31;
    const int zlo = (z > 0) ? z - 1 : 0;

    const int* hb = hist + (long)bh * NG3;
    const int* ob = offs + (long)bh * NG3;

    float acc0[16], acc1[16];
    #pragma unroll
    for (int c = 0; c < 16; ++c) { acc0[c] = 0.f; acc1[c] = 0.f; }

    #pragma unroll 1
    for (int pi = 0; pi < 3; ++pi) {
        int p = 2 * kp - 1 + pi;              // record plane
        if (p < 0) continue;                  // block-uniform (kp==0, pi==0)
        const bool u0 = (pi <= 1);            // contributes to plane 2kp
        const bool u1 = (pi >= 1);            // contributes to plane 2kp+1
        // segment bounds within this plane (merged z: cells (cy,zlo),(cy,z))
        int st[2], sp[2], en[2];
        #pragma unroll
        for (int dy = 0; dy < 2; ++dy) {
            int cy = y - dy;
            bool valid = cy >= 0;
            int base = (p << 10) | (cy << 5);
            int c1 = base | zlo;
            int c2 = base | z;
            st[dy] = valid ? ob[c1] : 0;
            sp[dy] = valid ? ob[c2] : 0;
            en[dy] = valid ? sp[dy] + hb[c2] : 0;
        }
        int pc0 = p << 10;
        int ps = ob[pc0];                     // uniform plane bounds
        int pe = ob[pc0 + 1023] + hb[pc0 + 1023];
        for (int cs = ps; cs < pe; cs += 1024) {
            int ce = min(cs + 1024, pe);
            __syncthreads();
            if (tid < ce - cs) {
                const uint4* R = rec + (long)(cs + tid) * 3;
                sr[tid * 3 + 0] = R[0];
                sr[tid * 3 + 1] = R[1];
                sr[tid * 3 + 2] = R[2];
            }
            __syncthreads();
            #pragma unroll
            for (int dy = 0; dy < 2; ++dy) {
                int ls = max(st[dy], cs);
                int le = min(en[dy], ce);
                int split = sp[dy];
                for (int r = ls; r < le; ++r) {
                    int k = (r - cs) * 3;
                    uint4 q0 = sr[k], q1 = sr[k + 1], q2 = sr[k + 2];
                    float fx = __uint_as_float(q0.x);
                    float fy = __uint_as_float(q0.y);
                    float fz = __uint_as_float(q0.z);
                    float wy = dy ? fy : 1.f - fy;
                    float wz = (r < split) ? fz : 1.f - fz;
                    float wyz = wy * wz;
                    float v[16];
                    v[0]  = bf_lo(q1.x); v[1]  = bf_hi(q1.x);
                    v[2]  = bf_lo(q1.y); v[3]  = bf_hi(q1.y);
                    v[4]  = bf_lo(q1.z); v[5]  = bf_hi(q1.z);
                    v[6]  = bf_lo(q1.w); v[7]  = bf_hi(q1.w);
                    v[8]  = bf_lo(q2.x); v[9]  = bf_hi(q2.x);
                    v[10] = bf_lo(q2.y); v[11] = bf_hi(q2.y);
                    v[12] = bf_lo(q2.z); v[13] = bf_hi(q2.z);
                    v[14] = bf_lo(q2.w); v[15] = bf_hi(q2.w);
                    if (u0) {
                        // out plane 2kp: dx = 2kp - p = (pi==0 ? 1 : 0)
                        float wx0 = (pi == 0) ? fx : 1.f - fx;
                        float w0 = wx0 * wyz;
                        #pragma unroll
                        for (int c = 0; c < 16; ++c)
                            acc0[c] = fmaf(w0, v[c], acc0[c]);
                    }
                    if (u1) {
                        // out plane 2kp+1: dx = 2kp+1 - p = (pi==1 ? 1 : 0)
                        float wx1 = (pi == 1) ? fx : 1.f - fx;
                        float w1 = wx1 * wyz;
                        #pragma unroll
                        for (int c = 0; c < 16; ++c)
                            acc1[c] = fmaf(w1, v[c], acc1[c]);
                    }
                }
            }
        }
    }

    {
        uint4 q0, q1;
        q0.x = pack_bf2(acc0[0],  acc0[1]);  q0.y = pack_bf2(acc0[2],  acc0[3]);
        q0.z = pack_bf2(acc0[4],  acc0[5]);  q0.w = pack_bf2(acc0[6],  acc0[7]);
        q1.x = pack_bf2(acc0[8],  acc0[9]);  q1.y = pack_bf2(acc0[10], acc0[11]);
        q1.z = pack_bf2(acc0[12], acc0[13]); q1.w = pack_bf2(acc0[14], acc0[15]);
        uint4* gb = (uint4*)(gridb + ((long)bh * NG3 + ((2 * kp) << 10) + tid) * NC);
        gb[0] = q0;
        gb[1] = q1;
    }
    {
        uint4 q0, q1;
        q0.x = pack_bf2(acc1[0],  acc1[1]);  q0.y = pack_bf2(acc1[2],  acc1[3]);
        q0.z = pack_bf2(acc1[4],  acc1[5]);  q0.w = pack_bf2(acc1[6],  acc1[7]);
        q1.x = pack_bf2(acc1[8],  acc1[9]);  q1.y = pack_bf2(acc1[10], acc1[11]);
        q1.z = pack_bf2(acc1[12], acc1[13]); q1.w = pack_bf2(acc1[14], acc1[15]);
        uint4* gb = (uint4*)(gridb + ((long)bh * NG3 + ((2 * kp + 1) << 10) + tid) * NC);
        gb[0] = q0;
        gb[1] = q1;
    }
}

// ---------------------------------------------------------------------------
// Kernel 3a: one-time weight conversion into conv's sw layout (bf16).
// ---------------------------------------------------------------------------
__global__ __launch_bounds__(256)
void k_wprep(const float* __restrict__ cw, unsigned short* __restrict__ wpre)
{
    const int h = blockIdx.x;
    for (int e = threadIdx.x; e < 7168; e += 256) {
        int icl = e & 7, oc = (e >> 3) & 15, ihl = (e >> 7) & 1, tap = e >> 8;
        int ic = ihl * 8 + icl;
        float wv = (tap < 27) ? cw[(h * 16 + oc) * 432 + ic * 27 + tap] : 0.f;
        __hip_bfloat16 hbw = __float2bfloat16(wv);
        wpre[h * 7168 + e] = *(unsigned short*)&hbw;
    }
}

// ---------------------------------------------------------------------------
// Kernel 3: grouped 3x3x3 conv via BF16 MFMA, fully-unrolled phase loop.
// ---------------------------------------------------------------------------
__global__ __launch_bounds__(512)
void k_conv5(const unsigned short* __restrict__ gridb,
             const unsigned short* __restrict__ wpre,
             const float* __restrict__ cb,
             unsigned short* __restrict__ convo)
{
    __shared__ unsigned short sg[2 * 6 * 10 * 34 * 8];  // 65280 B
    __shared__ unsigned short sw[28 * 2 * 16 * 8];      // 14336 B
    const int tid = threadIdx.x;
    const int bid = blockIdx.x;
    const int yt = bid & 3, xt = (bid >> 2) & 7, bh = bid >> 5;
    const int h = bh & 7;
    const int x0 = xt * 4, y0 = yt * 8;

    {
        const uint4* wsrc = (const uint4*)(wpre + (long)h * 7168);
        uint4* wdst = (uint4*)sw;
        for (int e = tid; e < 896; e += 512) wdst[e] = wsrc[e];
    }
    const unsigned short* gb = gridb + (long)bh * NG3 * 16;
    for (int e = tid; e < 2 * 6 * 10 * 34; e += 512) {
        int ihl = e & 1, c = e >> 1;
        int zz = c % 34, yu = c / 34;
        int yy = yu % 10, xx = yu / 10;
        int gx = x0 + xx - 1, gy = y0 + yy - 1, gz = zz - 1;
        uint4 v = make_uint4(0, 0, 0, 0);
        if ((unsigned)gx < NG && (unsigned)gy < NG && (unsigned)gz < NG)
            v = *(const uint4*)(gb + (((gx * NG + gy) * NG + gz) * 16 + ihl * 8));
        *(uint4*)(sg + ((((ihl * 6 + xx) * 10 + yy) * 34) + zz) * 8) = v;
    }
    __syncthreads();

    const int lane = tid & 63;
    const int w  = tid >> 6;
    const int wv = w & 3;
    const int zh = w >> 2;
    const int m  = lane & 15;
    const int l4 = lane >> 4;
    const int ihl = l4 & 1;
    const int tp = l4 >> 1;

    const int aLaneByte = ((((ihl * 6 + wv) * 10) * 34) + zh * 16 + m) * 16;
    const int bLaneByte = l4 * 256 + m * 16;
    const char* sgb = (const char*)sg;
    const char* swb = (const char*)sw;

    f32x4 acc[8];
    #pragma unroll
    for (int j = 0; j < 8; ++j) acc[j] = (f32x4){0.f, 0.f, 0.f, 0.f};

    #pragma unroll
    for (int p = 0; p < 14; ++p) {
        const int t0 = 2 * p, t1 = 2 * p + 1;
        const int ta0 = (t0 > 26) ? 26 : t0, ta1 = (t1 > 26) ? 26 : t1;
        const int off0 = ((ta0 / 9) * 340 + ((ta0 % 9) / 3) * 34 + (ta0 % 3)) * 16;
        const int off1 = ((ta1 / 9) * 340 + ((ta1 % 9) / 3) * 34 + (ta1 % 3)) * 16;
        const int aoff = aLaneByte + (tp ? off1 : off0);
        bf16x8 bfr = *(const bf16x8*)(swb + p * 1024 + bLaneByte);
        #pragma unroll
        for (int j = 0; j < 8; ++j) {
            bf16x8 afr = *(const bf16x8*)(sgb + aoff + j * 544);
            acc[j] = __builtin_amdgcn_mfma_f32_16x16x32_bf16(afr, bfr, acc[j], 0, 0, 0);
        }
    }

    const float bias = cb[h * 16 + m];
    unsigned short* cvb = convo + (long)bh * NG3 * NC;
    const int gx = x0 + wv;
    const int z0 = zh * 16;
    #pragma unroll
    for (int j = 0; j < 8; ++j) {
        int gy = y0 + j;
        long cellbase = (long)(gx * NG + gy) * NG + z0 + l4 * 4;
        #pragma unroll
        for (int r = 0; r < 4; ++r) {
            __hip_bfloat16 hb = __float2bfloat16(acc[j][r] + bias);
            cvb[(cellbase + r) * NC + m] = *(unsigned short*)&hb;
        }
    }
}

// ---------------------------------------------------------------------------
// Kernel 4: slice + BN + ReLU, out f32. XCD-grouped bh mapping.
// ---------------------------------------------------------------------------
__global__ __launch_bounds__(256)
void k_slice(const unsigned short* __restrict__ convo, const float4* __restrict__ pre,
             const float* __restrict__ ag, const float* __restrict__ ab,
             const float* __restrict__ am, const float* __restrict__ av,
             float* __restrict__ out)
{
    __shared__ float asc[128], ash[128];
    const int tid = threadIdx.x;
    if (tid < 128) {
        float s = rsqrtf(av[tid] + KEPS) * ag[tid];
        asc[tid] = s;
        ash[tid] = ab[tid] - am[tid] * s;
    }
    __syncthreads();

    const int bh   = 8 * ((blockIdx.x >> 3) & 3) + (blockIdx.x & 7);
    const int tile = blockIdx.x >> 5;
    const int n = tile * 256 + tid;
    long t = (long)bh * NN + n;
    int b = bh >> 3, h = bh & 7;
    const unsigned short* g = convo + (long)bh * NG3 * NC;

    float4 r = pre[t];
    int ibase = __float_as_int(r.x);
    float fx = r.y, fy = r.z, fz = r.w;
    float gx = 1.f - fx, gy = 1.f - fy, gz = 1.f - fz;
    const float ws8[8] = {gx*gy*gz, gx*gy*fz, gx*fy*gz, gx*fy*fz,
                          fx*gy*gz, fx*gy*fz, fx*fy*gz, fx*fy*fz};
    const int offs8[8] = {0, 1, NG, NG + 1, NG*NG, NG*NG + 1, NG*NG + NG, NG*NG + NG + 1};

    float acc[NC];
    #pragma unroll
    for (int c = 0; c < NC; ++c) acc[c] = 0.f;
    #pragma unroll
    for (int ci = 0; ci < 8; ++ci) {
        float w = ws8[ci];
        const uint4* gc = (const uint4*)(g + (long)(ibase + offs8[ci]) * NC);
        uint4 u0 = gc[0], u1 = gc[1];
        acc[0]  = fmaf(w, bf_lo(u0.x), acc[0]);
        acc[1]  = fmaf(w, bf_hi(u0.x), acc[1]);
        acc[2]  = fmaf(w, bf_lo(u0.y), acc[2]);
        acc[3]  = fmaf(w, bf_hi(u0.y), acc[3]);
        acc[4]  = fmaf(w, bf_lo(u0.z), acc[4]);
        acc[5]  = fmaf(w, bf_hi(u0.z), acc[5]);
        acc[6]  = fmaf(w, bf_lo(u0.w), acc[6]);
        acc[7]  = fmaf(w, bf_hi(u0.w), acc[7]);
        acc[8]  = fmaf(w, bf_lo(u1.x), acc[8]);
        acc[9]  = fmaf(w, bf_hi(u1.x), acc[9]);
        acc[10] = fmaf(w, bf_lo(u1.y), acc[10]);
        acc[11] = fmaf(w, bf_hi(u1.y), acc[11]);
        acc[12] = fmaf(w, bf_lo(u1.z), acc[12]);
        acc[13] = fmaf(w, bf_hi(u1.z), acc[13]);
        acc[14] = fmaf(w, bf_lo(u1.w), acc[14]);
        acc[15] = fmaf(w, bf_hi(u1.w), acc[15]);
    }
    float* ob = out + ((long)b * 128 + h * 16) * NN + n;
    #pragma unroll
    for (int c = 0; c < NC; ++c) {
        float rr = fmaf(acc[c], asc[h * 16 + c], ash[h * 16 + c]);
        ob[(long)c * NN] = fmaxf(rr, 0.f);
    }
}

// ---------------------------------------------------------------------------
extern "C" void kernel_launch(void* const* d_in, const int* in_sizes, int n_in,
                              void* d_out, int out_size, void* d_ws, size_t ws_size,
                              hipStream_t stream)
{
    (void)in_sizes; (void)n_in; (void)out_size; (void)ws_size;
    const float* x    = (const float*)d_in[0];
    const float* orig = (const float*)d_in[1];
    const float* wkv  = (const float*)d_in[2];
    const float* kg   = (const float*)d_in[3];
    const float* kb   = (const float*)d_in[4];
    const float* km   = (const float*)d_in[5];
    const float* kvv  = (const float*)d_in[6];
    const float* vg   = (const float*)d_in[7];
    const float* vb   = (const float*)d_in[8];
    const float* vm   = (const float*)d_in[9];
    const float* vv   = (const float*)d_in[10];
    const float* Wt   = (const float*)d_in[11];
    const float* bt   = (const float*)d_in[12];
    const float* cw   = (const float*)d_in[13];
    const float* cb   = (const float*)d_in[14];
    const float* ag   = (const float*)d_in[15];
    const float* ab   = (const float*)d_in[16];
    const float* am   = (const float*)d_in[17];
    const float* av   = (const float*)d_in[18];

    char* ws = (char*)d_ws;
    float4*         pre       = (float4*)        (ws);                 //  8,388,608
    int*            hist      = (int*)           (ws + 8388608);       //  4,194,304
    int*            offs      = (int*)           (ws + 12582912);      //  4,194,304
    int*            offs_live = (int*)           (ws + 16777216);      //  4,194,304
    unsigned short* valb      = (unsigned short*)(ws + 20971520);      // 16,777,216 -> end 37,748,736
    uint4*          rec       = (uint4*)         (ws + 37748736);      // 25,165,824 -> end 62,914,560
    unsigned short* gridb     = (unsigned short*)(ws + 62914560);      // 33,554,432 -> end 96,468,992
    unsigned short* wpre      = (unsigned short*)(ws + 96468992);      //    114,688 -> end 96,583,680
    unsigned short* convo     = (unsigned short*)(ws + 20971520);      // 33,554,432 (alias valb+rec, dead by k_conv5)

    k_zero<<<dim3(1024), dim3(256), 0, stream>>>((uint4*)hist);

    k_wprep<<<dim3(NH), dim3(256), 0, stream>>>(cw, wpre);

    k_front4<<<dim3(NB * 256), dim3(256), 0, stream>>>(
        x, orig, wkv, kg, kb, km, kvv, vg, vb, vm, vv, Wt, bt, valb, pre, hist);

    k_scan_cells<<<dim3(NB * NH), dim3(1024), 0, stream>>>(hist, offs, offs_live);

    k_scatter2<<<dim3((NB * NH * NN) / 256), dim3(256), 0, stream>>>(
        pre, valb, offs_live, rec);

    k_splat7<<<dim3(NB * NH * (NG / 2)), dim3(1024), 0, stream>>>(rec, hist, offs, gridb);

    k_conv5<<<dim3(NB * NH * 32), dim3(512), 0, stream>>>(gridb, wpre, cb, convo);

    k_slice<<<dim3((NB * NH * NN) / 256), dim3(256), 0, stream>>>(
        convo, pre, ag, ab, am, av, (float*)d_out);
}

// Round 18
// 197.072 us; speedup vs baseline: 1.0008x; 1.0008x over previous
//
#include <hip/hip_runtime.h>
#include <hip/hip_bf16.h>

#define NB  4
#define NH  8
#define NC  16
#define ND  64
#define NN  16384
#define NG  32
#define NG3 32768
#define NKV 152
#define KEPS 1e-5f
#define TN  256   // points per k_front3 block

typedef __attribute__((ext_vector_type(8))) short bf16x8;
typedef __attribute__((ext_vector_type(4))) float f32x4;

__device__ __forceinline__ unsigned pack_bf2(float lo, float hi) {
    __hip_bfloat16 a = __float2bfloat16(lo);
    __hip_bfloat16 b = __float2bfloat16(hi);
    return (unsigned)(*(unsigned short*)&a) | ((unsigned)(*(unsigned short*)&b) << 16);
}
__device__ __forceinline__ float bf_lo(unsigned u) { return __uint_as_float(u << 16); }
__device__ __forceinline__ float bf_hi(unsigned u) { return __uint_as_float(u & 0xffff0000u); }

// ---------------------------------------------------------------------------
// Kernel 0: fast zero of hist (4 MB).
// ---------------------------------------------------------------------------
__global__ __launch_bounds__(256)
void k_zero(uint4* __restrict__ p)
{
    p[(long)blockIdx.x * 256 + threadIdx.x] = make_uint4(0, 0, 0, 0);
}

// ---------------------------------------------------------------------------
// Kernel 1: front — 2 head-group blocks per point-tile (R15-proven config).
// ---------------------------------------------------------------------------
__global__ __launch_bounds__(256)
void k_front3(const float* __restrict__ x,      // [B,D,N]
              const float* __restrict__ orig,   // [B,3,N]
              const float* __restrict__ wkv,    // [152,64]
              const float* __restrict__ kg, const float* __restrict__ kb,
              const float* __restrict__ km, const float* __restrict__ kvv,
              const float* __restrict__ vg, const float* __restrict__ vb,
              const float* __restrict__ vm, const float* __restrict__ vv,
              const float* __restrict__ Wt,     // [8,3,3]
              const float* __restrict__ bt,     // [8,3]
              unsigned short* __restrict__ valb, // [B,H,N,C] bf16
              float4* __restrict__ pre,         // [B,H,N]
              int* __restrict__ hist)           // [B*H*32768]
{
    __shared__ unsigned short xb[TN * 72];      // bf16 x tile [n][d], pitch 72
    __shared__ float wk[12 * ND];               // this group's key rows
    __shared__ float ksc[12], ksh[12], vsc[64], vsh[64], wts[36], bts[12];
    const int tid = threadIdx.x;
    const int hg   = blockIdx.x & 1;            // head group: heads hg*4..hg*4+3
    const int tile = (blockIdx.x >> 1) & 63;
    const int b    = blockIdx.x >> 7;
    const int n0 = tile * TN;
    const int n  = n0 + tid;

    for (int i = tid; i < 12 * ND; i += 256) wk[i] = wkv[hg * 768 + i];
    if (tid < 12) {
        int ch = hg * 12 + tid;
        float s = rsqrtf(kvv[ch] + KEPS) * kg[ch];
        ksc[tid] = s;
        ksh[tid] = kb[ch] - km[ch] * s;
    }
    if (tid < 64) {
        int ch = hg * 64 + tid;
        float s = rsqrtf(vv[ch] + KEPS) * vg[ch];
        vsc[tid] = s;
        vsh[tid] = vb[ch] - vm[ch] * s;
    }
    if (tid < 36) wts[tid] = Wt[hg * 36 + tid];
    if (tid < 12) bts[tid] = bt[hg * 12 + tid];

    float xr[ND];
    #pragma unroll
    for (int d = 0; d < ND; ++d)
        xr[d] = x[((long)b * ND + d) * NN + n];
    #pragma unroll
    for (int j = 0; j < 8; ++j) {
        uint4 q;
        q.x = pack_bf2(xr[8*j+0], xr[8*j+1]);
        q.y = pack_bf2(xr[8*j+2], xr[8*j+3]);
        q.z = pack_bf2(xr[8*j+4], xr[8*j+5]);
        q.w = pack_bf2(xr[8*j+6], xr[8*j+7]);
        *(uint4*)(xb + tid * 72 + j * 8) = q;
    }
    __syncthreads();

    float ko[12];
    #pragma unroll 1
    for (int o = 0; o < 12; o += 4) {
        float s0 = 0.f, s1 = 0.f, s2 = 0.f, s3 = 0.f;
        #pragma unroll
        for (int dq = 0; dq < 16; ++dq) {
            const float4 w0 = *(const float4*)&wk[(o + 0) * ND + dq * 4];
            const float4 w1 = *(const float4*)&wk[(o + 1) * ND + dq * 4];
            const float4 w2 = *(const float4*)&wk[(o + 2) * ND + dq * 4];
            const float4 w3 = *(const float4*)&wk[(o + 3) * ND + dq * 4];
            float a0 = xr[4*dq], a1 = xr[4*dq+1], a2 = xr[4*dq+2], a3 = xr[4*dq+3];
            s0 = fmaf(w0.x, a0, fmaf(w0.y, a1, fmaf(w0.z, a2, fmaf(w0.w, a3, s0))));
            s1 = fmaf(w1.x, a0, fmaf(w1.y, a1, fmaf(w1.z, a2, fmaf(w1.w, a3, s1))));
            s2 = fmaf(w2.x, a0, fmaf(w2.y, a1, fmaf(w2.z, a2, fmaf(w2.w, a3, s2))));
            s3 = fmaf(w3.x, a0, fmaf(w3.y, a1, fmaf(w3.z, a2, fmaf(w3.w, a3, s3))));
        }
        ko[o + 0] = fmaf(s0, ksc[o + 0], ksh[o + 0]);
        ko[o + 1] = fmaf(s1, ksc[o + 1], ksh[o + 1]);
        ko[o + 2] = fmaf(s2, ksc[o + 2], ksh[o + 2]);
        ko[o + 3] = fmaf(s3, ksc[o + 3], ksh[o + 3]);
    }

    {
        const int lane = tid & 63;
        const int wv = tid >> 6;
        const int l15 = lane & 15, l4 = lane >> 4;
        const int h = hg * 4 + wv;
        const int ocg = h * 16 + l15;
        const float bsc = vsc[wv * 16 + l15];
        const float bsh = vsh[wv * 16 + l15];

        bf16x8 bfr[2];
        #pragma unroll
        for (int ks = 0; ks < 2; ++ks) {
            const float* wp = wkv + (24 + ocg) * ND + ks * 32 + l4 * 8;
            float4 a = *(const float4*)wp;
            float4 c = *(const float4*)(wp + 4);
            uint4 q;
            q.x = pack_bf2(a.x, a.y); q.y = pack_bf2(a.z, a.w);
            q.z = pack_bf2(c.x, c.y); q.w = pack_bf2(c.z, c.w);
            bfr[ks] = *(bf16x8*)&q;
        }

        #pragma unroll 1
        for (int nb = 0; nb < 16; ++nb) {
            bf16x8 a0 = *(const bf16x8*)(xb + (nb * 16 + l15) * 72 + l4 * 8);
            bf16x8 a1 = *(const bf16x8*)(xb + (nb * 16 + l15) * 72 + 32 + l4 * 8);
            f32x4 acc = (f32x4){0.f, 0.f, 0.f, 0.f};
            acc = __builtin_amdgcn_mfma_f32_16x16x32_bf16(a0, bfr[0], acc, 0, 0, 0);
            acc = __builtin_amdgcn_mfma_f32_16x16x32_bf16(a1, bfr[1], acc, 0, 0, 0);
            unsigned short* vp = valb + (((long)(b * NH + h) * NN + n0 + nb * 16 + l4 * 4) * NC) + l15;
            #pragma unroll
            for (int r = 0; r < 4; ++r) {
                __hip_bfloat16 hb = __float2bfloat16(fmaf(acc[r], bsc, bsh));
                vp[r * NC] = *(unsigned short*)&hb;
            }
        }
    }

    const float o0 = orig[((long)b * 3 + 0) * NN + n];
    const float o1 = orig[((long)b * 3 + 1) * NN + n];
    const float o2 = orig[((long)b * 3 + 2) * NN + n];

    #pragma unroll 1
    for (int lh = 0; lh < 4; ++lh) {
        float p0 = o0 + ko[lh * 3 + 0];
        float p1 = o1 + ko[lh * 3 + 1];
        float p2 = o2 + ko[lh * 3 + 2];
        float t0 = fmaf(wts[lh * 9 + 0], p0, fmaf(wts[lh * 9 + 1], p1, fmaf(wts[lh * 9 + 2], p2, bts[lh * 3 + 0])));
        float t1 = fmaf(wts[lh * 9 + 3], p0, fmaf(wts[lh * 9 + 4], p1, fmaf(wts[lh * 9 + 5], p2, bts[lh * 3 + 1])));
        float t2 = fmaf(wts[lh * 9 + 6], p0, fmaf(wts[lh * 9 + 7], p1, fmaf(wts[lh * 9 + 8], p2, bts[lh * 3 + 2])));
        float l0 = tanhf(t0), l1 = tanhf(t1), l2 = tanhf(t2);
        float pos0 = (l0 + 1.f) * 15.5f;
        float pos1 = (l1 + 1.f) * 15.5f;
        float pos2 = (l2 + 1.f) * 15.5f;
        float b0 = fminf(fmaxf(floorf(pos0), 0.f), 30.f);
        float b1 = fminf(fmaxf(floorf(pos1), 0.f), 30.f);
        float b2 = fminf(fmaxf(floorf(pos2), 0.f), 30.f);
        int ix = (int)b0, iy = (int)b1, iz = (int)b2;
        float fx = pos0 - b0, fy = pos1 - b1, fz = pos2 - b2;
        int ibase = (ix * NG + iy) * NG + iz;
        float4 pr;
        pr.x = __int_as_float(ibase);
        pr.y = fx; pr.z = fy; pr.w = fz;
        int bh = b * NH + hg * 4 + lh;
        pre[(long)bh * NN + n] = pr;
        atomicAdd(&hist[bh * NG3 + ibase], 1);
    }
}

// ---------------------------------------------------------------------------
// Kernel 1b: per-bh exclusive prefix scan over 32768 cell counts.
// ---------------------------------------------------------------------------
__global__ __launch_bounds__(1024)
void k_scan_cells(const int* __restrict__ hist, int* __restrict__ offs,
                  int* __restrict__ offs_live)
{
    __shared__ int tsum[1024];
    const int bh = blockIdx.x, tid = threadIdx.x;
    const int* hb = hist + (long)bh * NG3;

    int s = 0;
    #pragma unroll 4
    for (int j = 0; j < 32; ++j) s += hb[tid * 32 + j];
    tsum[tid] = s;
    __syncthreads();
    for (int d = 1; d < 1024; d <<= 1) {
        int t = (tid >= d) ? tsum[tid - d] : 0;
        __syncthreads();
        tsum[tid] += t;
        __syncthreads();
    }
    int run = bh * NN + tsum[tid] - s;
    int* ob = offs + (long)bh * NG3;
    int* lb = offs_live + (long)bh * NG3;
    #pragma unroll 4
    for (int j = 0; j < 32; ++j) {
        int c = tid * 32 + j;
        ob[c] = run;
        lb[c] = run;
        run += hb[c];
    }
}

// ---------------------------------------------------------------------------
// Kernel 1c: scatter records into cell order. Record = 3 x uint4 = 48 B.
// XCD-grouped bh mapping (4-bh working set per XCD).
// ---------------------------------------------------------------------------
__global__ __launch_bounds__(256)
void k_scatter2(const float4* __restrict__ pre, const unsigned short* __restrict__ valb,
                int* __restrict__ offs_live, uint4* __restrict__ rec)
{
    const int bh   = 8 * ((blockIdx.x >> 3) & 3) + (blockIdx.x & 7);
    const int tile = blockIdx.x >> 5;
    long t = (long)bh * NN + tile * 256 + threadIdx.x;
    float4 r = pre[t];
    int ibase = __float_as_int(r.x);
    int slot = atomicAdd(&offs_live[(long)bh * NG3 + ibase], 1);
    const uint4* vp = (const uint4*)(valb + t * NC);
    uint4 v0 = vp[0], v1 = vp[1];
    uint4* out = rec + (long)slot * 3;
    out[0] = make_uint4(__float_as_uint(r.y), __float_as_uint(r.z), __float_as_uint(r.w), 0u);
    out[1] = v0;
    out[2] = v1;
}

// ---------------------------------------------------------------------------
// Kernel 2: splat8 — splat6 structure (R15 decode) + unpack-at-stage:
// staging threads decode each bf16 record ONCE into an 80 B f32 LDS record
// (512-record chunks, 40 KB); visit loop is pure ds_read_b128 + FMA
// (per-visit VALU ~24 vs ~37; unpack amortized 8 visits -> 1).
// ---------------------------------------------------------------------------
__global__ __launch_bounds__(1024)
void k_splat8(const uint4* __restrict__ rec, const int* __restrict__ hist,
              const int* __restrict__ offs, unsigned short* __restrict__ gridb)
{
    __shared__ float sf[512 * 20];   // 40 KB: [rec][fx,fy,fz,pad,v0..v15]
    const int tid = threadIdx.x;
    const int rx = blockIdx.x & 31;
    const int bh = blockIdx.x >> 5;
    const int y = tid >> 5, z = tid & 31;
    const int zlo = (z > 0) ? z - 1 : 0;

    const int* hb = hist + (long)bh * NG3;
    const int* ob = offs + (long)bh * NG3;

    float acc[16];
    #pragma unroll
    for (int c = 0; c < 16; ++c) acc[c] = 0.f;

    #pragma unroll
    for (int dx = 0; dx < 2; ++dx) {
        int cx = rx - dx;
        if (cx < 0) continue;                       // block-uniform
        int st[2], sp[2], en[2];
        #pragma unroll
        for (int dy = 0; dy < 2; ++dy) {
            int cy = y - dy;
            bool valid = cy >= 0;
            int base = (cx << 10) | (cy << 5);
            int c1 = base | zlo;
            int c2 = base | z;
            st[dy] = valid ? ob[c1] : 0;
            sp[dy] = valid ? ob[c2] : 0;
            en[dy] = valid ? sp[dy] + hb[c2] : 0;
        }
        int pc0 = cx << 10;
        int ps = ob[pc0];                           // uniform plane bounds
        int pe = ob[pc0 + 1023] + hb[pc0 + 1023];
        for (int cs = ps; cs < pe; cs += 512) {
            int ce = min(cs + 512, pe);
            __syncthreads();
            if (tid < ce - cs) {
                const uint4* R = rec + (long)(cs + tid) * 3;
                uint4 q0 = R[0], q1 = R[1], q2 = R[2];
                float* d = sf + tid * 20;
                d[0] = __uint_as_float(q0.x);
                d[1] = __uint_as_float(q0.y);
                d[2] = __uint_as_float(q0.z);
                d[3] = 0.f;
                d[4]  = bf_lo(q1.x); d[5]  = bf_hi(q1.x);
                d[6]  = bf_lo(q1.y); d[7]  = bf_hi(q1.y);
                d[8]  = bf_lo(q1.z); d[9]  = bf_hi(q1.z);
                d[10] = bf_lo(q1.w); d[11] = bf_hi(q1.w);
                d[12] = bf_lo(q2.x); d[13] = bf_hi(q2.x);
                d[14] = bf_lo(q2.y); d[15] = bf_hi(q2.y);
                d[16] = bf_lo(q2.z); d[17] = bf_hi(q2.z);
                d[18] = bf_lo(q2.w); d[19] = bf_hi(q2.w);
            }
            __syncthreads();
            #pragma unroll
            for (int dy = 0; dy < 2; ++dy) {
                int ls = max(st[dy], cs);
                int le = min(en[dy], ce);
                int split = sp[dy];
                for (int r = ls; r < le; ++r) {
                    const float* R = sf + (r - cs) * 20;
                    float4 h0 = *(const float4*)(R);
                    float4 v0 = *(const float4*)(R + 4);
                    float4 v1 = *(const float4*)(R + 8);
                    float4 v2 = *(const float4*)(R + 12);
                    float4 v3 = *(const float4*)(R + 16);
                    float wx = dx ? h0.x : 1.f - h0.x;
                    float wy = dy ? h0.y : 1.f - h0.y;
                    float wz = (r < split) ? h0.z : 1.f - h0.z;
                    float w = wx * wy * wz;
                    acc[0]  = fmaf(w, v0.x, acc[0]);
                    acc[1]  = fmaf(w, v0.y, acc[1]);
                    acc[2]  = fmaf(w, v0.z, acc[2]);
                    acc[3]  = fmaf(w, v0.w, acc[3]);
                    acc[4]  = fmaf(w, v1.x, acc[4]);
                    acc[5]  = fmaf(w, v1.y, acc[5]);
                    acc[6]  = fmaf(w, v1.z, acc[6]);
                    acc[7]  = fmaf(w, v1.w, acc[7]);
                    acc[8]  = fmaf(w, v2.x, acc[8]);
                    acc[9]  = fmaf(w, v2.y, acc[9]);
                    acc[10] = fmaf(w, v2.z, acc[10]);
                    acc[11] = fmaf(w, v2.w, acc[11]);
                    acc[12] = fmaf(w, v3.x, acc[12]);
                    acc[13] = fmaf(w, v3.y, acc[13]);
                    acc[14] = fmaf(w, v3.z, acc[14]);
                    acc[15] = fmaf(w, v3.w, acc[15]);
                }
            }
        }
    }

    uint4 q0, q1;
    q0.x = pack_bf2(acc[0],  acc[1]);  q0.y = pack_bf2(acc[2],  acc[3]);
    q0.z = pack_bf2(acc[4],  acc[5]);  q0.w = pack_bf2(acc[6],  acc[7]);
    q1.x = pack_bf2(acc[8],  acc[9]);  q1.y = pack_bf2(acc[10], acc[11]);
    q1.z = pack_bf2(acc[12], acc[13]); q1.w = pack_bf2(acc[14], acc[15]);
    uint4* gb = (uint4*)(gridb + ((long)bh * NG3 + (rx << 10) + tid) * NC);
    gb[0] = q0;
    gb[1] = q1;
}

// ---------------------------------------------------------------------------
// Kernel 3a: one-time weight conversion into conv's sw layout (bf16).
// ---------------------------------------------------------------------------
__global__ __launch_bounds__(256)
void k_wprep(const float* __restrict__ cw, unsigned short* __restrict__ wpre)
{
    const int h = blockIdx.x;
    for (int e = threadIdx.x; e < 7168; e += 256) {
        int icl = e & 7, oc = (e >> 3) & 15, ihl = (e >> 7) & 1, tap = e >> 8;
        int ic = ihl * 8 + icl;
        float wv = (tap < 27) ? cw[(h * 16 + oc) * 432 + ic * 27 + tap] : 0.f;
        __hip_bfloat16 hbw = __float2bfloat16(wv);
        wpre[h * 7168 + e] = *(unsigned short*)&hbw;
    }
}

// ---------------------------------------------------------------------------
// Kernel 3: grouped 3x3x3 conv via BF16 MFMA, fully-unrolled phase loop.
// ---------------------------------------------------------------------------
__global__ __launch_bounds__(512)
void k_conv5(const unsigned short* __restrict__ gridb,
             const unsigned short* __restrict__ wpre,
             const float* __restrict__ cb,
             unsigned short* __restrict__ convo)
{
    __shared__ unsigned short sg[2 * 6 * 10 * 34 * 8];  // 65280 B
    __shared__ unsigned short sw[28 * 2 * 16 * 8];      // 14336 B
    const int tid = threadIdx.x;
    const int bid = blockIdx.x;
    const int yt = bid & 3, xt = (bid >> 2) & 7, bh = bid >> 5;
    const int h = bh & 7;
    const int x0 = xt * 4, y0 = yt * 8;

    {
        const uint4* wsrc = (const uint4*)(wpre + (long)h * 7168);
        uint4* wdst = (uint4*)sw;
        for (int e = tid; e < 896; e += 512) wdst[e] = wsrc[e];
    }
    const unsigned short* gb = gridb + (long)bh * NG3 * 16;
    for (int e = tid; e < 2 * 6 * 10 * 34; e += 512) {
        int ihl = e & 1, c = e >> 1;
        int zz = c % 34, yu = c / 34;
        int yy = yu % 10, xx = yu / 10;
        int gx = x0 + xx - 1, gy = y0 + yy - 1, gz = zz - 1;
        uint4 v = make_uint4(0, 0, 0, 0);
        if ((unsigned)gx < NG && (unsigned)gy < NG && (unsigned)gz < NG)
            v = *(const uint4*)(gb + (((gx * NG + gy) * NG + gz) * 16 + ihl * 8));
        *(uint4*)(sg + ((((ihl * 6 + xx) * 10 + yy) * 34) + zz) * 8) = v;
    }
    __syncthreads();

    const int lane = tid & 63;
    const int w  = tid >> 6;
    const int wv = w & 3;
    const int zh = w >> 2;
    const int m  = lane & 15;
    const int l4 = lane >> 4;
    const int ihl = l4 & 1;
    const int tp = l4 >> 1;

    const int aLaneByte = ((((ihl * 6 + wv) * 10) * 34) + zh * 16 + m) * 16;
    const int bLaneByte = l4 * 256 + m * 16;
    const char* sgb = (const char*)sg;
    const char* swb = (const char*)sw;

    f32x4 acc[8];
    #pragma unroll
    for (int j = 0; j < 8; ++j) acc[j] = (f32x4){0.f, 0.f, 0.f, 0.f};

    #pragma unroll
    for (int p = 0; p < 14; ++p) {
        const int t0 = 2 * p, t1 = 2 * p + 1;
        const int ta0 = (t0 > 26) ? 26 : t0, ta1 = (t1 > 26) ? 26 : t1;
        const int off0 = ((ta0 / 9) * 340 + ((ta0 % 9) / 3) * 34 + (ta0 % 3)) * 16;
        const int off1 = ((ta1 / 9) * 340 + ((ta1 % 9) / 3) * 34 + (ta1 % 3)) * 16;
        const int aoff = aLaneByte + (tp ? off1 : off0);
        bf16x8 bfr = *(const bf16x8*)(swb + p * 1024 + bLaneByte);
        #pragma unroll
        for (int j = 0; j < 8; ++j) {
            bf16x8 afr = *(const bf16x8*)(sgb + aoff + j * 544);
            acc[j] = __builtin_amdgcn_mfma_f32_16x16x32_bf16(afr, bfr, acc[j], 0, 0, 0);
        }
    }

    const float bias = cb[h * 16 + m];
    unsigned short* cvb = convo + (long)bh * NG3 * NC;
    const int gx = x0 + wv;
    const int z0 = zh * 16;
    #pragma unroll
    for (int j = 0; j < 8; ++j) {
        int gy = y0 + j;
        long cellbase = (long)(gx * NG + gy) * NG + z0 + l4 * 4;
        #pragma unroll
        for (int r = 0; r < 4; ++r) {
            __hip_bfloat16 hb = __float2bfloat16(acc[j][r] + bias);
            cvb[(cellbase + r) * NC + m] = *(unsigned short*)&hb;
        }
    }
}

// ---------------------------------------------------------------------------
// Kernel 4: slice + BN + ReLU, out f32. XCD-grouped bh mapping.
// ---------------------------------------------------------------------------
__global__ __launch_bounds__(256)
void k_slice(const unsigned short* __restrict__ convo, const float4* __restrict__ pre,
             const float* __restrict__ ag, const float* __restrict__ ab,
             const float* __restrict__ am, const float* __restrict__ av,
             float* __restrict__ out)
{
    __shared__ float asc[128], ash[128];
    const int tid = threadIdx.x;
    if (tid < 128) {
        float s = rsqrtf(av[tid] + KEPS) * ag[tid];
        asc[tid] = s;
        ash[tid] = ab[tid] - am[tid] * s;
    }
    __syncthreads();

    const int bh   = 8 * ((blockIdx.x >> 3) & 3) + (blockIdx.x & 7);
    const int tile = blockIdx.x >> 5;
    const int n = tile * 256 + tid;
    long t = (long)bh * NN + n;
    int b = bh >> 3, h = bh & 7;
    const unsigned short* g = convo + (long)bh * NG3 * NC;

    float4 r = pre[t];
    int ibase = __float_as_int(r.x);
    float fx = r.y, fy = r.z, fz = r.w;
    float gx = 1.f - fx, gy = 1.f - fy, gz = 1.f - fz;
    const float ws8[8] = {gx*gy*gz, gx*gy*fz, gx*fy*gz, gx*fy*fz,
                          fx*gy*gz, fx*gy*fz, fx*fy*gz, fx*fy*fz};
    const int offs8[8] = {0, 1, NG, NG + 1, NG*NG, NG*NG + 1, NG*NG + NG, NG*NG + NG + 1};

    float acc[NC];
    #pragma unroll
    for (int c = 0; c < NC; ++c) acc[c] = 0.f;
    #pragma unroll
    for (int ci = 0; ci < 8; ++ci) {
        float w = ws8[ci];
        const uint4* gc = (const uint4*)(g + (long)(ibase + offs8[ci]) * NC);
        uint4 u0 = gc[0], u1 = gc[1];
        acc[0]  = fmaf(w, bf_lo(u0.x), acc[0]);
        acc[1]  = fmaf(w, bf_hi(u0.x), acc[1]);
        acc[2]  = fmaf(w, bf_lo(u0.y), acc[2]);
        acc[3]  = fmaf(w, bf_hi(u0.y), acc[3]);
        acc[4]  = fmaf(w, bf_lo(u0.z), acc[4]);
        acc[5]  = fmaf(w, bf_hi(u0.z), acc[5]);
        acc[6]  = fmaf(w, bf_lo(u0.w), acc[6]);
        acc[7]  = fmaf(w, bf_hi(u0.w), acc[7]);
        acc[8]  = fmaf(w, bf_lo(u1.x), acc[8]);
        acc[9]  = fmaf(w, bf_hi(u1.x), acc[9]);
        acc[10] = fmaf(w, bf_lo(u1.y), acc[10]);
        acc[11] = fmaf(w, bf_hi(u1.y), acc[11]);
        acc[12] = fmaf(w, bf_lo(u1.z), acc[12]);
        acc[13] = fmaf(w, bf_hi(u1.z), acc[13]);
        acc[14] = fmaf(w, bf_lo(u1.w), acc[14]);
        acc[15] = fmaf(w, bf_hi(u1.w), acc[15]);
    }
    float* ob = out + ((long)b * 128 + h * 16) * NN + n;
    #pragma unroll
    for (int c = 0; c < NC; ++c) {
        float rr = fmaf(acc[c], asc[h * 16 + c], ash[h * 16 + c]);
        ob[(long)c * NN] = fmaxf(rr, 0.f);
    }
}

// ---------------------------------------------------------------------------
extern "C" void kernel_launch(void* const* d_in, const int* in_sizes, int n_in,
                              void* d_out, int out_size, void* d_ws, size_t ws_size,
                              hipStream_t stream)
{
    (void)in_sizes; (void)n_in; (void)out_size; (void)ws_size;
    const float* x    = (const float*)d_in[0];
    const float* orig = (const float*)d_in[1];
    const float* wkv  = (const float*)d_in[2];
    const float* kg   = (const float*)d_in[3];
    const float* kb   = (const float*)d_in[4];
    const float* km   = (const float*)d_in[5];
    const float* kvv  = (const float*)d_in[6];
    const float* vg   = (const float*)d_in[7];
    const float* vb   = (const float*)d_in[8];
    const float* vm   = (const float*)d_in[9];
    const float* vv   = (const float*)d_in[10];
    const float* Wt   = (const float*)d_in[11];
    const float* bt   = (const float*)d_in[12];
    const float* cw   = (const float*)d_in[13];
    const float* cb   = (const float*)d_in[14];
    const float* ag   = (const float*)d_in[15];
    const float* ab   = (const float*)d_in[16];
    const float* am   = (const float*)d_in[17];
    const float* av   = (const float*)d_in[18];

    char* ws = (char*)d_ws;
    float4*         pre       = (float4*)        (ws);                 //  8,388,608
    int*            hist      = (int*)           (ws + 8388608);       //  4,194,304
    int*            offs      = (int*)           (ws + 12582912);      //  4,194,304
    int*            offs_live = (int*)           (ws + 16777216);      //  4,194,304
    unsigned short* valb      = (unsigned short*)(ws + 20971520);      // 16,777,216 -> end 37,748,736
    uint4*          rec       = (uint4*)         (ws + 37748736);      // 25,165,824 -> end 62,914,560
    unsigned short* gridb     = (unsigned short*)(ws + 62914560);      // 33,554,432 -> end 96,468,992
    unsigned short* wpre      = (unsigned short*)(ws + 96468992);      //    114,688 -> end 96,583,680
    unsigned short* convo     = (unsigned short*)(ws + 20971520);      // 33,554,432 (alias valb+rec, dead by k_conv5)

    k_zero<<<dim3(1024), dim3(256), 0, stream>>>((uint4*)hist);

    k_wprep<<<dim3(NH), dim3(256), 0, stream>>>(cw, wpre);

    k_front3<<<dim3(NB * 128), dim3(256), 0, stream>>>(
        x, orig, wkv, kg, kb, km, kvv, vg, vb, vm, vv, Wt, bt, valb, pre, hist);

    k_scan_cells<<<dim3(NB * NH), dim3(1024), 0, stream>>>(hist, offs, offs_live);

    k_scatter2<<<dim3((NB * NH * NN) / 256), dim3(256), 0, stream>>>(
        pre, valb, offs_live, rec);

    k_splat8<<<dim3(NB * NH * NG), dim3(1024), 0, stream>>>(rec, hist, offs, gridb);

    k_conv5<<<dim3(NB * NH * 32), dim3(512), 0, stream>>>(gridb, wpre, cb, convo);

    k_slice<<<dim3((NB * NH * NN) / 256), dim3(256), 0, stream>>>(
        convo, pre, ag, ab, am, av, (float*)d_out);
}

// Round 19
// 195.160 us; speedup vs baseline: 1.0106x; 1.0098x over previous
//
#include <hip/hip_runtime.h>
#include <hip/hip_bf16.h>

#define NB  4
#define NH  8
#define NC  16
#define ND  64
#define NN  16384
#define NG  32
#define NG3 32768
#define NKV 152
#define KEPS 1e-5f
#define TN  256   // points per k_front3 block

typedef __attribute__((ext_vector_type(8))) short bf16x8;
typedef __attribute__((ext_vector_type(4))) float f32x4;

__device__ __forceinline__ unsigned pack_bf2(float lo, float hi) {
    __hip_bfloat16 a = __float2bfloat16(lo);
    __hip_bfloat16 b = __float2bfloat16(hi);
    return (unsigned)(*(unsigned short*)&a) | ((unsigned)(*(unsigned short*)&b) << 16);
}
__device__ __forceinline__ float bf_lo(unsigned u) { return __uint_as_float(u << 16); }
__device__ __forceinline__ float bf_hi(unsigned u) { return __uint_as_float(u & 0xffff0000u); }

// ---------------------------------------------------------------------------
// Kernel 0: init — blocks 0..7 convert weights (wprep), blocks 8..1031 zero
// the 4 MB histogram. One launch instead of two.
// ---------------------------------------------------------------------------
__global__ __launch_bounds__(256)
void k_init(const float* __restrict__ cw, unsigned short* __restrict__ wpre,
            uint4* __restrict__ histq)
{
    if (blockIdx.x < 8) {
        const int h = blockIdx.x;
        for (int e = threadIdx.x; e < 7168; e += 256) {
            int icl = e & 7, oc = (e >> 3) & 15, ihl = (e >> 7) & 1, tap = e >> 8;
            int ic = ihl * 8 + icl;
            float wv = (tap < 27) ? cw[(h * 16 + oc) * 432 + ic * 27 + tap] : 0.f;
            __hip_bfloat16 hbw = __float2bfloat16(wv);
            wpre[h * 7168 + e] = *(unsigned short*)&hbw;
        }
    } else {
        histq[(long)(blockIdx.x - 8) * 256 + threadIdx.x] = make_uint4(0, 0, 0, 0);
    }
}

// ---------------------------------------------------------------------------
// Kernel 1: front — 2 head-group blocks per point-tile (R15-proven config).
// ---------------------------------------------------------------------------
__global__ __launch_bounds__(256)
void k_front3(const float* __restrict__ x,      // [B,D,N]
              const float* __restrict__ orig,   // [B,3,N]
              const float* __restrict__ wkv,    // [152,64]
              const float* __restrict__ kg, const float* __restrict__ kb,
              const float* __restrict__ km, const float* __restrict__ kvv,
              const float* __restrict__ vg, const float* __restrict__ vb,
              const float* __restrict__ vm, const float* __restrict__ vv,
              const float* __restrict__ Wt,     // [8,3,3]
              const float* __restrict__ bt,     // [8,3]
              unsigned short* __restrict__ valb, // [B,H,N,C] bf16
              float4* __restrict__ pre,         // [B,H,N]
              int* __restrict__ hist)           // [B*H*32768]
{
    __shared__ unsigned short xb[TN * 72];      // bf16 x tile [n][d], pitch 72
    __shared__ float wk[12 * ND];               // this group's key rows
    __shared__ float ksc[12], ksh[12], vsc[64], vsh[64], wts[36], bts[12];
    const int tid = threadIdx.x;
    const int hg   = blockIdx.x & 1;            // head group: heads hg*4..hg*4+3
    const int tile = (blockIdx.x >> 1) & 63;
    const int b    = blockIdx.x >> 7;
    const int n0 = tile * TN;
    const int n  = n0 + tid;

    for (int i = tid; i < 12 * ND; i += 256) wk[i] = wkv[hg * 768 + i];
    if (tid < 12) {
        int ch = hg * 12 + tid;
        float s = rsqrtf(kvv[ch] + KEPS) * kg[ch];
        ksc[tid] = s;
        ksh[tid] = kb[ch] - km[ch] * s;
    }
    if (tid < 64) {
        int ch = hg * 64 + tid;
        float s = rsqrtf(vv[ch] + KEPS) * vg[ch];
        vsc[tid] = s;
        vsh[tid] = vb[ch] - vm[ch] * s;
    }
    if (tid < 36) wts[tid] = Wt[hg * 36 + tid];
    if (tid < 12) bts[tid] = bt[hg * 12 + tid];

    float xr[ND];
    #pragma unroll
    for (int d = 0; d < ND; ++d)
        xr[d] = x[((long)b * ND + d) * NN + n];
    #pragma unroll
    for (int j = 0; j < 8; ++j) {
        uint4 q;
        q.x = pack_bf2(xr[8*j+0], xr[8*j+1]);
        q.y = pack_bf2(xr[8*j+2], xr[8*j+3]);
        q.z = pack_bf2(xr[8*j+4], xr[8*j+5]);
        q.w = pack_bf2(xr[8*j+6], xr[8*j+7]);
        *(uint4*)(xb + tid * 72 + j * 8) = q;
    }
    __syncthreads();

    float ko[12];
    #pragma unroll 1
    for (int o = 0; o < 12; o += 4) {
        float s0 = 0.f, s1 = 0.f, s2 = 0.f, s3 = 0.f;
        #pragma unroll
        for (int dq = 0; dq < 16; ++dq) {
            const float4 w0 = *(const float4*)&wk[(o + 0) * ND + dq * 4];
            const float4 w1 = *(const float4*)&wk[(o + 1) * ND + dq * 4];
            const float4 w2 = *(const float4*)&wk[(o + 2) * ND + dq * 4];
            const float4 w3 = *(const float4*)&wk[(o + 3) * ND + dq * 4];
            float a0 = xr[4*dq], a1 = xr[4*dq+1], a2 = xr[4*dq+2], a3 = xr[4*dq+3];
            s0 = fmaf(w0.x, a0, fmaf(w0.y, a1, fmaf(w0.z, a2, fmaf(w0.w, a3, s0))));
            s1 = fmaf(w1.x, a0, fmaf(w1.y, a1, fmaf(w1.z, a2, fmaf(w1.w, a3, s1))));
            s2 = fmaf(w2.x, a0, fmaf(w2.y, a1, fmaf(w2.z, a2, fmaf(w2.w, a3, s2))));
            s3 = fmaf(w3.x, a0, fmaf(w3.y, a1, fmaf(w3.z, a2, fmaf(w3.w, a3, s3))));
        }
        ko[o + 0] = fmaf(s0, ksc[o + 0], ksh[o + 0]);
        ko[o + 1] = fmaf(s1, ksc[o + 1], ksh[o + 1]);
        ko[o + 2] = fmaf(s2, ksc[o + 2], ksh[o + 2]);
        ko[o + 3] = fmaf(s3, ksc[o + 3], ksh[o + 3]);
    }

    {
        const int lane = tid & 63;
        const int wv = tid >> 6;
        const int l15 = lane & 15, l4 = lane >> 4;
        const int h = hg * 4 + wv;
        const int ocg = h * 16 + l15;
        const float bsc = vsc[wv * 16 + l15];
        const float bsh = vsh[wv * 16 + l15];

        bf16x8 bfr[2];
        #pragma unroll
        for (int ks = 0; ks < 2; ++ks) {
            const float* wp = wkv + (24 + ocg) * ND + ks * 32 + l4 * 8;
            float4 a = *(const float4*)wp;
            float4 c = *(const float4*)(wp + 4);
            uint4 q;
            q.x = pack_bf2(a.x, a.y); q.y = pack_bf2(a.z, a.w);
            q.z = pack_bf2(c.x, c.y); q.w = pack_bf2(c.z, c.w);
            bfr[ks] = *(bf16x8*)&q;
        }

        #pragma unroll 1
        for (int nb = 0; nb < 16; ++nb) {
            bf16x8 a0 = *(const bf16x8*)(xb + (nb * 16 + l15) * 72 + l4 * 8);
            bf16x8 a1 = *(const bf16x8*)(xb + (nb * 16 + l15) * 72 + 32 + l4 * 8);
            f32x4 acc = (f32x4){0.f, 0.f, 0.f, 0.f};
            acc = __builtin_amdgcn_mfma_f32_16x16x32_bf16(a0, bfr[0], acc, 0, 0, 0);
            acc = __builtin_amdgcn_mfma_f32_16x16x32_bf16(a1, bfr[1], acc, 0, 0, 0);
            unsigned short* vp = valb + (((long)(b * NH + h) * NN + n0 + nb * 16 + l4 * 4) * NC) + l15;
            #pragma unroll
            for (int r = 0; r < 4; ++r) {
                __hip_bfloat16 hb = __float2bfloat16(fmaf(acc[r], bsc, bsh));
                vp[r * NC] = *(unsigned short*)&hb;
            }
        }
    }

    const float o0 = orig[((long)b * 3 + 0) * NN + n];
    const float o1 = orig[((long)b * 3 + 1) * NN + n];
    const float o2 = orig[((long)b * 3 + 2) * NN + n];

    #pragma unroll 1
    for (int lh = 0; lh < 4; ++lh) {
        float p0 = o0 + ko[lh * 3 + 0];
        float p1 = o1 + ko[lh * 3 + 1];
        float p2 = o2 + ko[lh * 3 + 2];
        float t0 = fmaf(wts[lh * 9 + 0], p0, fmaf(wts[lh * 9 + 1], p1, fmaf(wts[lh * 9 + 2], p2, bts[lh * 3 + 0])));
        float t1 = fmaf(wts[lh * 9 + 3], p0, fmaf(wts[lh * 9 + 4], p1, fmaf(wts[lh * 9 + 5], p2, bts[lh * 3 + 1])));
        float t2 = fmaf(wts[lh * 9 + 6], p0, fmaf(wts[lh * 9 + 7], p1, fmaf(wts[lh * 9 + 8], p2, bts[lh * 3 + 2])));
        float l0 = tanhf(t0), l1 = tanhf(t1), l2 = tanhf(t2);
        float pos0 = (l0 + 1.f) * 15.5f;
        float pos1 = (l1 + 1.f) * 15.5f;
        float pos2 = (l2 + 1.f) * 15.5f;
        float b0 = fminf(fmaxf(floorf(pos0), 0.f), 30.f);
        float b1 = fminf(fmaxf(floorf(pos1), 0.f), 30.f);
        float b2 = fminf(fmaxf(floorf(pos2), 0.f), 30.f);
        int ix = (int)b0, iy = (int)b1, iz = (int)b2;
        float fx = pos0 - b0, fy = pos1 - b1, fz = pos2 - b2;
        int ibase = (ix * NG + iy) * NG + iz;
        float4 pr;
        pr.x = __int_as_float(ibase);
        pr.y = fx; pr.z = fy; pr.w = fz;
        int bh = b * NH + hg * 4 + lh;
        pre[(long)bh * NN + n] = pr;
        atomicAdd(&hist[bh * NG3 + ibase], 1);
    }
}

// ---------------------------------------------------------------------------
// Kernel 1b: per-bh exclusive prefix scan over 32768 cell counts.
// ---------------------------------------------------------------------------
__global__ __launch_bounds__(1024)
void k_scan_cells(const int* __restrict__ hist, int* __restrict__ offs,
                  int* __restrict__ offs_live)
{
    __shared__ int tsum[1024];
    const int bh = blockIdx.x, tid = threadIdx.x;
    const int* hb = hist + (long)bh * NG3;

    int s = 0;
    #pragma unroll 4
    for (int j = 0; j < 32; ++j) s += hb[tid * 32 + j];
    tsum[tid] = s;
    __syncthreads();
    for (int d = 1; d < 1024; d <<= 1) {
        int t = (tid >= d) ? tsum[tid - d] : 0;
        __syncthreads();
        tsum[tid] += t;
        __syncthreads();
    }
    int run = bh * NN + tsum[tid] - s;
    int* ob = offs + (long)bh * NG3;
    int* lb = offs_live + (long)bh * NG3;
    #pragma unroll 4
    for (int j = 0; j < 32; ++j) {
        int c = tid * 32 + j;
        ob[c] = run;
        lb[c] = run;
        run += hb[c];
    }
}

// ---------------------------------------------------------------------------
// Kernel 1c: scatter records into cell order. Record = 3 x uint4 = 48 B.
// XCD-grouped bh mapping (4-bh working set per XCD).
// ---------------------------------------------------------------------------
__global__ __launch_bounds__(256)
void k_scatter2(const float4* __restrict__ pre, const unsigned short* __restrict__ valb,
                int* __restrict__ offs_live, uint4* __restrict__ rec)
{
    const int bh   = 8 * ((blockIdx.x >> 3) & 3) + (blockIdx.x & 7);
    const int tile = blockIdx.x >> 5;
    long t = (long)bh * NN + tile * 256 + threadIdx.x;
    float4 r = pre[t];
    int ibase = __float_as_int(r.x);
    int slot = atomicAdd(&offs_live[(long)bh * NG3 + ibase], 1);
    const uint4* vp = (const uint4*)(valb + t * NC);
    uint4 v0 = vp[0], v1 = vp[1];
    uint4* out = rec + (long)slot * 3;
    out[0] = make_uint4(__float_as_uint(r.y), __float_as_uint(r.z), __float_as_uint(r.w), 0u);
    out[1] = v0;
    out[2] = v1;
}

// ---------------------------------------------------------------------------
// Kernel 2: splat6 — LDS-staged chunks, merged-z segments. Atomic-free.
// (R15-proven: rx = blk & 31, bh = blk >> 5.)
// ---------------------------------------------------------------------------
__global__ __launch_bounds__(1024)
void k_splat6(const uint4* __restrict__ rec, const int* __restrict__ hist,
              const int* __restrict__ offs, unsigned short* __restrict__ gridb)
{
    __shared__ uint4 sr[1024 * 3];   // 48 KB chunk
    const int tid = threadIdx.x;
    const int rx = blockIdx.x & 31;
    const int bh = blockIdx.x >> 5;
    const int y = tid >> 5, z = tid & 31;
    const int zlo = (z > 0) ? z - 1 : 0;

    const int* hb = hist + (long)bh * NG3;
    const int* ob = offs + (long)bh * NG3;

    float acc[16];
    #pragma unroll
    for (int c = 0; c < 16; ++c) acc[c] = 0.f;

    #pragma unroll
    for (int dx = 0; dx < 2; ++dx) {
        int cx = rx - dx;
        if (cx < 0) continue;                       // block-uniform
        int st[2], sp[2], en[2];
        #pragma unroll
        for (int dy = 0; dy < 2; ++dy) {
            int cy = y - dy;
            bool valid = cy >= 0;
            int base = (cx << 10) | (cy << 5);
            int c1 = base | zlo;
            int c2 = base | z;
            st[dy] = valid ? ob[c1] : 0;
            sp[dy] = valid ? ob[c2] : 0;
            en[dy] = valid ? sp[dy] + hb[c2] : 0;
        }
        int pc0 = cx << 10;
        int ps = ob[pc0];                           // uniform plane bounds
        int pe = ob[pc0 + 1023] + hb[pc0 + 1023];
        for (int cs = ps; cs < pe; cs += 1024) {
            int ce = min(cs + 1024, pe);
            __syncthreads();
            if (tid < ce - cs) {
                const uint4* R = rec + (long)(cs + tid) * 3;
                sr[tid * 3 + 0] = R[0];
                sr[tid * 3 + 1] = R[1];
                sr[tid * 3 + 2] = R[2];
            }
            __syncthreads();
            #pragma unroll
            for (int dy = 0; dy < 2; ++dy) {
                int ls = max(st[dy], cs);
                int le = min(en[dy], ce);
                int split = sp[dy];
                for (int r = ls; r < le; ++r) {
                    int k = (r - cs) * 3;
                    uint4 q0 = sr[k], q1 = sr[k + 1], q2 = sr[k + 2];
                    float fx = __uint_as_float(q0.x);
                    float fy = __uint_as_float(q0.y);
                    float fz = __uint_as_float(q0.z);
                    float wx = dx ? fx : 1.f - fx;
                    float wy = dy ? fy : 1.f - fy;
                    float wz = (r < split) ? fz : 1.f - fz;
                    float w = wx * wy * wz;
                    acc[0]  = fmaf(w, bf_lo(q1.x), acc[0]);
                    acc[1]  = fmaf(w, bf_hi(q1.x), acc[1]);
                    acc[2]  = fmaf(w, bf_lo(q1.y), acc[2]);
                    acc[3]  = fmaf(w, bf_hi(q1.y), acc[3]);
                    acc[4]  = fmaf(w, bf_lo(q1.z), acc[4]);
                    acc[5]  = fmaf(w, bf_hi(q1.z), acc[5]);
                    acc[6]  = fmaf(w, bf_lo(q1.w), acc[6]);
                    acc[7]  = fmaf(w, bf_hi(q1.w), acc[7]);
                    acc[8]  = fmaf(w, bf_lo(q2.x), acc[8]);
                    acc[9]  = fmaf(w, bf_hi(q2.x), acc[9]);
                    acc[10] = fmaf(w, bf_lo(q2.y), acc[10]);
                    acc[11] = fmaf(w, bf_hi(q2.y), acc[11]);
                    acc[12] = fmaf(w, bf_lo(q2.z), acc[12]);
                    acc[13] = fmaf(w, bf_hi(q2.z), acc[13]);
                    acc[14] = fmaf(w, bf_lo(q2.w), acc[14]);
                    acc[15] = fmaf(w, bf_hi(q2.w), acc[15]);
                }
            }
        }
    }

    uint4 q0, q1;
    q0.x = pack_bf2(acc[0],  acc[1]);  q0.y = pack_bf2(acc[2],  acc[3]);
    q0.z = pack_bf2(acc[4],  acc[5]);  q0.w = pack_bf2(acc[6],  acc[7]);
    q1.x = pack_bf2(acc[8],  acc[9]);  q1.y = pack_bf2(acc[10], acc[11]);
    q1.z = pack_bf2(acc[12], acc[13]); q1.w = pack_bf2(acc[14], acc[15]);
    uint4* gb = (uint4*)(gridb + ((long)bh * NG3 + (rx << 10) + tid) * NC);
    gb[0] = q0;
    gb[1] = q1;
}

// ---------------------------------------------------------------------------
// Kernel 3: grouped 3x3x3 conv via BF16 MFMA, fully-unrolled phase loop.
// ---------------------------------------------------------------------------
__global__ __launch_bounds__(512)
void k_conv5(const unsigned short* __restrict__ gridb,
             const unsigned short* __restrict__ wpre,
             const float* __restrict__ cb,
             unsigned short* __restrict__ convo)
{
    __shared__ unsigned short sg[2 * 6 * 10 * 34 * 8];  // 65280 B
    __shared__ unsigned short sw[28 * 2 * 16 * 8];      // 14336 B
    const int tid = threadIdx.x;
    const int bid = blockIdx.x;
    const int yt = bid & 3, xt = (bid >> 2) & 7, bh = bid >> 5;
    const int h = bh & 7;
    const int x0 = xt * 4, y0 = yt * 8;

    {
        const uint4* wsrc = (const uint4*)(wpre + (long)h * 7168);
        uint4* wdst = (uint4*)sw;
        for (int e = tid; e < 896; e += 512) wdst[e] = wsrc[e];
    }
    const unsigned short* gb = gridb + (long)bh * NG3 * 16;
    for (int e = tid; e < 2 * 6 * 10 * 34; e += 512) {
        int ihl = e & 1, c = e >> 1;
        int zz = c % 34, yu = c / 34;
        int yy = yu % 10, xx = yu / 10;
        int gx = x0 + xx - 1, gy = y0 + yy - 1, gz = zz - 1;
        uint4 v = make_uint4(0, 0, 0, 0);
        if ((unsigned)gx < NG && (unsigned)gy < NG && (unsigned)gz < NG)
            v = *(const uint4*)(gb + (((gx * NG + gy) * NG + gz) * 16 + ihl * 8));
        *(uint4*)(sg + ((((ihl * 6 + xx) * 10 + yy) * 34) + zz) * 8) = v;
    }
    __syncthreads();

    const int lane = tid & 63;
    const int w  = tid >> 6;
    const int wv = w & 3;
    const int zh = w >> 2;
    const int m  = lane & 15;
    const int l4 = lane >> 4;
    const int ihl = l4 & 1;
    const int tp = l4 >> 1;

    const int aLaneByte = ((((ihl * 6 + wv) * 10) * 34) + zh * 16 + m) * 16;
    const int bLaneByte = l4 * 256 + m * 16;
    const char* sgb = (const char*)sg;
    const char* swb = (const char*)sw;

    f32x4 acc[8];
    #pragma unroll
    for (int j = 0; j < 8; ++j) acc[j] = (f32x4){0.f, 0.f, 0.f, 0.f};

    #pragma unroll
    for (int p = 0; p < 14; ++p) {
        const int t0 = 2 * p, t1 = 2 * p + 1;
        const int ta0 = (t0 > 26) ? 26 : t0, ta1 = (t1 > 26) ? 26 : t1;
        const int off0 = ((ta0 / 9) * 340 + ((ta0 % 9) / 3) * 34 + (ta0 % 3)) * 16;
        const int off1 = ((ta1 / 9) * 340 + ((ta1 % 9) / 3) * 34 + (ta1 % 3)) * 16;
        const int aoff = aLaneByte + (tp ? off1 : off0);
        bf16x8 bfr = *(const bf16x8*)(swb + p * 1024 + bLaneByte);
        #pragma unroll
        for (int j = 0; j < 8; ++j) {
            bf16x8 afr = *(const bf16x8*)(sgb + aoff + j * 544);
            acc[j] = __builtin_amdgcn_mfma_f32_16x16x32_bf16(afr, bfr, acc[j], 0, 0, 0);
        }
    }

    const float bias = cb[h * 16 + m];
    unsigned short* cvb = convo + (long)bh * NG3 * NC;
    const int gx = x0 + wv;
    const int z0 = zh * 16;
    #pragma unroll
    for (int j = 0; j < 8; ++j) {
        int gy = y0 + j;
        long cellbase = (long)(gx * NG + gy) * NG + z0 + l4 * 4;
        #pragma unroll
        for (int r = 0; r < 4; ++r) {
            __hip_bfloat16 hb = __float2bfloat16(acc[j][r] + bias);
            cvb[(cellbase + r) * NC + m] = *(unsigned short*)&hb;
        }
    }
}

// ---------------------------------------------------------------------------
// Kernel 4: slice2 — 2 points per thread (independent interleaved gather
// chains double memory-level parallelism). XCD-grouped bh mapping.
// ---------------------------------------------------------------------------
__global__ __launch_bounds__(256)
void k_slice2(const unsigned short* __restrict__ convo, const float4* __restrict__ pre,
              const float* __restrict__ ag, const float* __restrict__ ab,
              const float* __restrict__ am, const float* __restrict__ av,
              float* __restrict__ out)
{
    __shared__ float asc[128], ash[128];
    const int tid = threadIdx.x;
    if (tid < 128) {
        float s = rsqrtf(av[tid] + KEPS) * ag[tid];
        asc[tid] = s;
        ash[tid] = ab[tid] - am[tid] * s;
    }
    __syncthreads();

    const int bh   = 8 * ((blockIdx.x >> 3) & 3) + (blockIdx.x & 7);
    const int tile = blockIdx.x >> 5;          // [0, 32)
    const int n1 = tile * 512 + tid;
    const int n2 = n1 + 256;
    const int b = bh >> 3, h = bh & 7;
    const unsigned short* g = convo + (long)bh * NG3 * NC;

    float4 r1 = pre[(long)bh * NN + n1];
    float4 r2 = pre[(long)bh * NN + n2];
    int ib1 = __float_as_int(r1.x);
    int ib2 = __float_as_int(r2.x);
    float fx1 = r1.y, fy1 = r1.z, fz1 = r1.w;
    float fx2 = r2.y, fy2 = r2.z, fz2 = r2.w;
    float gx1 = 1.f - fx1, gy1 = 1.f - fy1, gz1 = 1.f - fz1;
    float gx2 = 1.f - fx2, gy2 = 1.f - fy2, gz2 = 1.f - fz2;
    const float wa[8] = {gx1*gy1*gz1, gx1*gy1*fz1, gx1*fy1*gz1, gx1*fy1*fz1,
                         fx1*gy1*gz1, fx1*gy1*fz1, fx1*fy1*gz1, fx1*fy1*fz1};
    const float wb[8] = {gx2*gy2*gz2, gx2*gy2*fz2, gx2*fy2*gz2, gx2*fy2*fz2,
                         fx2*gy2*gz2, fx2*gy2*fz2, fx2*fy2*gz2, fx2*fy2*fz2};
    const int offs8[8] = {0, 1, NG, NG + 1, NG*NG, NG*NG + 1, NG*NG + NG, NG*NG + NG + 1};

    float a1[NC], a2[NC];
    #pragma unroll
    for (int c = 0; c < NC; ++c) { a1[c] = 0.f; a2[c] = 0.f; }
    #pragma unroll
    for (int ci = 0; ci < 8; ++ci) {
        const uint4* g1 = (const uint4*)(g + (long)(ib1 + offs8[ci]) * NC);
        const uint4* g2 = (const uint4*)(g + (long)(ib2 + offs8[ci]) * NC);
        uint4 p0 = g1[0], p1 = g1[1];
        uint4 q0 = g2[0], q1 = g2[1];
        float w1 = wa[ci], w2 = wb[ci];
        a1[0]  = fmaf(w1, bf_lo(p0.x), a1[0]);   a2[0]  = fmaf(w2, bf_lo(q0.x), a2[0]);
        a1[1]  = fmaf(w1, bf_hi(p0.x), a1[1]);   a2[1]  = fmaf(w2, bf_hi(q0.x), a2[1]);
        a1[2]  = fmaf(w1, bf_lo(p0.y), a1[2]);   a2[2]  = fmaf(w2, bf_lo(q0.y), a2[2]);
        a1[3]  = fmaf(w1, bf_hi(p0.y), a1[3]);   a2[3]  = fmaf(w2, bf_hi(q0.y), a2[3]);
        a1[4]  = fmaf(w1, bf_lo(p0.z), a1[4]);   a2[4]  = fmaf(w2, bf_lo(q0.z), a2[4]);
        a1[5]  = fmaf(w1, bf_hi(p0.z), a1[5]);   a2[5]  = fmaf(w2, bf_hi(q0.z), a2[5]);
        a1[6]  = fmaf(w1, bf_lo(p0.w), a1[6]);   a2[6]  = fmaf(w2, bf_lo(q0.w), a2[6]);
        a1[7]  = fmaf(w1, bf_hi(p0.w), a1[7]);   a2[7]  = fmaf(w2, bf_hi(q0.w), a2[7]);
        a1[8]  = fmaf(w1, bf_lo(p1.x), a1[8]);   a2[8]  = fmaf(w2, bf_lo(q1.x), a2[8]);
        a1[9]  = fmaf(w1, bf_hi(p1.x), a1[9]);   a2[9]  = fmaf(w2, bf_hi(q1.x), a2[9]);
        a1[10] = fmaf(w1, bf_lo(p1.y), a1[10]);  a2[10] = fmaf(w2, bf_lo(q1.y), a2[10]);
        a1[11] = fmaf(w1, bf_hi(p1.y), a1[11]);  a2[11] = fmaf(w2, bf_hi(q1.y), a2[11]);
        a1[12] = fmaf(w1, bf_lo(p1.z), a1[12]);  a2[12] = fmaf(w2, bf_lo(q1.z), a2[12]);
        a1[13] = fmaf(w1, bf_hi(p1.z), a1[13]);  a2[13] = fmaf(w2, bf_hi(q1.z), a2[13]);
        a1[14] = fmaf(w1, bf_lo(p1.w), a1[14]);  a2[14] = fmaf(w2, bf_lo(q1.w), a2[14]);
        a1[15] = fmaf(w1, bf_hi(p1.w), a1[15]);  a2[15] = fmaf(w2, bf_hi(q1.w), a2[15]);
    }
    float* ob1 = out + ((long)b * 128 + h * 16) * NN + n1;
    float* ob2 = out + ((long)b * 128 + h * 16) * NN + n2;
    #pragma unroll
    for (int c = 0; c < NC; ++c) {
        float s = asc[h * 16 + c], sh = ash[h * 16 + c];
        ob1[(long)c * NN] = fmaxf(fmaf(a1[c], s, sh), 0.f);
        ob2[(long)c * NN] = fmaxf(fmaf(a2[c], s, sh), 0.f);
    }
}

// ---------------------------------------------------------------------------
extern "C" void kernel_launch(void* const* d_in, const int* in_sizes, int n_in,
                              void* d_out, int out_size, void* d_ws, size_t ws_size,
                              hipStream_t stream)
{
    (void)in_sizes; (void)n_in; (void)out_size; (void)ws_size;
    const float* x    = (const float*)d_in[0];
    const float* orig = (const float*)d_in[1];
    const float* wkv  = (const float*)d_in[2];
    const float* kg   = (const float*)d_in[3];
    const float* kb   = (const float*)d_in[4];
    const float* km   = (const float*)d_in[5];
    const float* kvv  = (const float*)d_in[6];
    const float* vg   = (const float*)d_in[7];
    const float* vb   = (const float*)d_in[8];
    const float* vm   = (const float*)d_in[9];
    const float* vv   = (const float*)d_in[10];
    const float* Wt   = (const float*)d_in[11];
    const float* bt   = (const float*)d_in[12];
    const float* cw   = (const float*)d_in[13];
    const float* cb   = (const float*)d_in[14];
    const float* ag   = (const float*)d_in[15];
    const float* ab   = (const float*)d_in[16];
    const float* am   = (const float*)d_in[17];
    const float* av   = (const float*)d_in[18];

    char* ws = (char*)d_ws;
    float4*         pre       = (float4*)        (ws);                 //  8,388,608
    int*            hist      = (int*)           (ws + 8388608);       //  4,194,304
    int*            offs      = (int*)           (ws + 12582912);      //  4,194,304
    int*            offs_live = (int*)           (ws + 16777216);      //  4,194,304
    unsigned short* valb      = (unsigned short*)(ws + 20971520);      // 16,777,216 -> end 37,748,736
    uint4*          rec       = (uint4*)         (ws + 37748736);      // 25,165,824 -> end 62,914,560
    unsigned short* gridb     = (unsigned short*)(ws + 62914560);      // 33,554,432 -> end 96,468,992
    unsigned short* wpre      = (unsigned short*)(ws + 96468992);      //    114,688 -> end 96,583,680
    unsigned short* convo     = (unsigned short*)(ws + 20971520);      // 33,554,432 (alias valb+rec, dead by k_conv5)

    k_init<<<dim3(8 + 1024), dim3(256), 0, stream>>>(cw, wpre, (uint4*)hist);

    k_front3<<<dim3(NB * 128), dim3(256), 0, stream>>>(
        x, orig, wkv, kg, kb, km, kvv, vg, vb, vm, vv, Wt, bt, valb, pre, hist);

    k_scan_cells<<<dim3(NB * NH), dim3(1024), 0, stream>>>(hist, offs, offs_live);

    k_scatter2<<<dim3((NB * NH * NN) / 256), dim3(256), 0, stream>>>(
        pre, valb, offs_live, rec);

    k_splat6<<<dim3(NB * NH * NG), dim3(1024), 0, stream>>>(rec, hist, offs, gridb);

    k_conv5<<<dim3(NB * NH * 32), dim3(512), 0, stream>>>(gridb, wpre, cb, convo);

    k_slice2<<<dim3((NB * NH * NN) / 512), dim3(256), 0, stream>>>(
        convo, pre, ag, ab, am, av, (float*)d_out);
}